// Round 5
// baseline (1592.958 us; speedup 1.0000x reference)
//
#include <hip/hip_runtime.h>

// OnlineLSTM: B=8192, T=2048, I=1, H=50.
// Block = 32 batch rows = 2 independent groups of 16, 4 waves (256 thr),
// grid = 256 = 1 block/CU, 1 wave/SIMD. Each wave owns j-columns
// 16w..16w+15 (all 4 gates) for BOTH groups: the two groups' MFMA + gate
// chains are interleaved in ONE instruction stream -> latency hiding by ILP
// (R4 showed cross-block TLP does not phase-offset; both blocks stalled
// together at their barriers). Weights (B fragments) are shared by both
// groups, so the marginal cost of group 2 is pure independent issue.
// K padded 50->64; k=50 carries x_t, k=51 carries 1.0 so MFMA output IS the
// exp2 argument (weights prescaled by -log2e for i,f,o / +2log2e for g).
// Gate algebra: common-denominator form, 7 transcendentals per (b,j).

#define HID   50
#define NSTEP 2048
#define GPB   2      // batch groups per block
#define BPB   32     // batch rows per block
#define HSTR  72     // fp16 elems per hbuf row

typedef _Float16 half8   __attribute__((ext_vector_type(8)));
typedef float    float4v __attribute__((ext_vector_type(4)));

__device__ __forceinline__ float gate_pair(float zi, float zf, float zg, float zo,
                                           float& c) {
    // zi,zf,zo = -log2e * raw;  zg = 2log2e * raw  (prescaled in weights)
    float ei = __builtin_amdgcn_exp2f(zi);   // e^{-i_raw}
    float ef = __builtin_amdgcn_exp2f(zf);
    float Eg = __builtin_amdgcn_exp2f(zg);   // e^{2 g_raw}
    float eo = __builtin_amdgcn_exp2f(zo);
    float t1  = (1.0f + ei) * (1.0f + Eg);
    float num = c * t1 + (1.0f + ef) * (Eg - 1.0f);
    float D   = t1 * (1.0f + ef);
    c = num * __builtin_amdgcn_rcpf(D);
    float a  = fminf(fmaxf(2.8853900817779268f * c, -24.0f), 24.0f);
    float Ec = __builtin_amdgcn_exp2f(a);    // e^{2c}
    return (Ec - 1.0f) * __builtin_amdgcn_rcpf((1.0f + eo) * (1.0f + Ec));
}

__global__ __launch_bounds__(256, 1) void lstm_fused(
    const float* __restrict__ x,
    const float* __restrict__ W_ih,
    const float* __restrict__ W_hh,
    const float* __restrict__ b_ih,
    const float* __restrict__ b_hh,
    const float* __restrict__ W_lin,
    const float* __restrict__ b_lin,
    float* __restrict__ out)
{
    __shared__ __align__(16) _Float16 hbuf[GPB][2][16][HSTR];

    const int tid  = threadIdx.x;
    const int wave = tid >> 6;
    const int lane = tid & 63;
    const int col  = lane & 15;
    const int quad = lane >> 4;
    const int b0   = blockIdx.x * BPB;
    const int j    = wave * 16 + col;

    // ---- init h buffers: zeros, x_0 at col 50, 1.0 at col 51 ----
    for (int i = tid; i < GPB * 2 * 16 * HSTR; i += 256)
        (&hbuf[0][0][0][0])[i] = (_Float16)0.0f;
    __syncthreads();
    if (tid < BPB) {
        int g = tid >> 4, r = tid & 15;
        hbuf[g][0][r][HID]     = (_Float16)x[(size_t)(b0 + tid) * NSTEP];
        hbuf[g][0][r][HID + 1] = (_Float16)1.0f;
        hbuf[g][1][r][HID + 1] = (_Float16)1.0f;
    }

    // ---- persistent B fragments (shared by both groups), prescaled ----
    const float LOG2E = 1.4426950408889634f;
    half8 bfrag[4][2];
    for (int g = 0; g < 4; ++g) {
        const float sc = (g == 2) ? (2.0f * LOG2E) : (-LOG2E);
        for (int kt = 0; kt < 2; ++kt) {
            half8 f;
            #pragma unroll
            for (int jj = 0; jj < 8; ++jj) {
                int k = kt * 32 + quad * 8 + jj;
                float v = 0.0f;
                if (j < HID) {
                    int row = g * HID + j;
                    if (k < HID)           v = W_hh[row * HID + k];
                    else if (k == HID)     v = W_ih[row];
                    else if (k == HID + 1) v = b_ih[row] + b_hh[row];
                }
                f[jj] = (_Float16)(v * sc);
            }
            bfrag[g][kt] = f;
        }
    }

    float c0[4] = {0.f, 0.f, 0.f, 0.f};
    float c1[4] = {0.f, 0.f, 0.f, 0.f};
    const bool xl = (wave < GPB) && (quad == 0);  // wave g loads x for group g
    const float* xrow = x + (size_t)(b0 + wave * 16 + col) * NSTEP;
    const float4v Z4 = {0.f, 0.f, 0.f, 0.f};

    __syncthreads();

#define MFMA16(A, B, C) __builtin_amdgcn_mfma_f32_16x16x32_f16(A, B, C, 0, 0, 0)
#define STEP(CUR, NXT, T)                                                        \
    {                                                                            \
        float xn = 0.f;                                                          \
        if (xl) {                                                                \
            int tt = ((T) + 1 < NSTEP) ? ((T) + 1) : (NSTEP - 1);                \
            xn = xrow[tt];                                                       \
        }                                                                        \
        const _Float16* ar0 = &hbuf[0][CUR][col][0];                             \
        const _Float16* ar1 = &hbuf[1][CUR][col][0];                             \
        half8 a00 = *(const half8*)(ar0 + quad * 8);                             \
        half8 a10 = *(const half8*)(ar1 + quad * 8);                             \
        half8 a01 = *(const half8*)(ar0 + 32 + quad * 8);                        \
        half8 a11 = *(const half8*)(ar1 + 32 + quad * 8);                        \
        float4v e0, e1, e2, e3, f0, f1, f2, f3;                                  \
        e0 = MFMA16(a00, bfrag[0][0], Z4);  f0 = MFMA16(a10, bfrag[0][0], Z4);   \
        e1 = MFMA16(a00, bfrag[1][0], Z4);  f1 = MFMA16(a10, bfrag[1][0], Z4);   \
        e2 = MFMA16(a00, bfrag[2][0], Z4);  f2 = MFMA16(a10, bfrag[2][0], Z4);   \
        e3 = MFMA16(a00, bfrag[3][0], Z4);  f3 = MFMA16(a10, bfrag[3][0], Z4);   \
        e0 = MFMA16(a01, bfrag[0][1], e0);  f0 = MFMA16(a11, bfrag[0][1], f0);   \
        e1 = MFMA16(a01, bfrag[1][1], e1);  f1 = MFMA16(a11, bfrag[1][1], f1);   \
        e2 = MFMA16(a01, bfrag[2][1], e2);  f2 = MFMA16(a11, bfrag[2][1], f2);   \
        e3 = MFMA16(a01, bfrag[3][1], e3);  f3 = MFMA16(a11, bfrag[3][1], f3);   \
        _Float16 hv0[4], hv1[4];                                                 \
        _Pragma("unroll")                                                        \
        for (int r = 0; r < 4; ++r) {                                            \
            hv0[r] = (_Float16)gate_pair(e0[r], e1[r], e2[r], e3[r], c0[r]);     \
            hv1[r] = (_Float16)gate_pair(f0[r], f1[r], f2[r], f3[r], c1[r]);     \
        }                                                                        \
        if (j < HID) {                                                           \
            _Pragma("unroll")                                                    \
            for (int r = 0; r < 4; ++r) {                                        \
                hbuf[0][NXT][quad * 4 + r][j] = hv0[r];                          \
                hbuf[1][NXT][quad * 4 + r][j] = hv1[r];                          \
            }                                                                    \
        }                                                                        \
        if (xl)                                                                  \
            hbuf[wave][NXT][col][HID] = (_Float16)xn;                            \
        __syncthreads();                                                         \
    }

    for (int t = 0; t < NSTEP; t += 2) {
        STEP(0, 1, t)
        STEP(1, 0, t + 1)
    }
#undef STEP
#undef MFMA16

    // ---- epilogue: out[b] = h_last . W_lin + b_lin ; final h in phase 0 ----
    if (tid < BPB) {
        int g = tid >> 4, r = tid & 15;
        float s = b_lin[0];
        for (int k = 0; k < HID; ++k)
            s += (float)hbuf[g][0][r][k] * W_lin[k];
        out[b0 + tid] = s;
    }
}

extern "C" void kernel_launch(void* const* d_in, const int* in_sizes, int n_in,
                              void* d_out, int out_size, void* d_ws, size_t ws_size,
                              hipStream_t stream) {
    const float* x     = (const float*)d_in[0];
    const float* W_ih  = (const float*)d_in[1];
    const float* W_hh  = (const float*)d_in[2];
    const float* b_ih  = (const float*)d_in[3];
    const float* b_hh  = (const float*)d_in[4];
    const float* W_lin = (const float*)d_in[5];
    const float* b_lin = (const float*)d_in[6];
    float* outp = (float*)d_out;
    dim3 grid(8192 / BPB), block(256);
    hipLaunchKernelGGL(lstm_fused, grid, block, 0, stream,
                       x, W_ih, W_hh, b_ih, b_hh, W_lin, b_lin, outp);
}

// Round 6
// 1425.942 us; speedup vs baseline: 1.1171x; 1.1171x over previous
//
#include <hip/hip_runtime.h>

// OnlineLSTM: B=8192, T=2048, I=1, H=50.
// Block = 8 batch rows, 4 waves (256 thr), grid = 1024 = 4 blocks/CU: each
// SIMD hosts 4 waves from 4 DIFFERENT barrier domains -> stalls interleave
// (R4 showed 2-way gives 63% issue efficiency; R5 showed 1 wave/SIMD can't
// hide anything). Batch rows sit in EVEN MFMA A-rows (m = 2b): C-layout rows
// quad*4+r are valid exactly for r in {0,2}, so gate math is 2 full-wave
// slots (14 transc/wave) — same per-SIMD issue as R4, spread over 2x waves.
// Wave jt owns j-columns 16jt..16jt+15 for ALL 4 gates (gate-major N=256).
// K padded 50->64; k=50 carries x_t, k=51 carries 1.0 so MFMA output IS the
// exp2 argument (weights prescaled by -log2e for i,f,o / +2log2e for g).
// Gate algebra: common-denominator form, 7 transcendentals per (b,j).

#define HID   50
#define NSTEP 2048
#define BPB   8      // batch rows per block (even A-rows 0,2,..,14)
#define HSTR  72     // fp16 elems per hbuf row

typedef _Float16 half8   __attribute__((ext_vector_type(8)));
typedef float    float4v __attribute__((ext_vector_type(4)));

__device__ __forceinline__ float gate_pair(float zi, float zf, float zg, float zo,
                                           float& c) {
    // zi,zf,zo = -log2e * raw;  zg = 2log2e * raw  (prescaled in weights)
    float ei = __builtin_amdgcn_exp2f(zi);   // e^{-i_raw}
    float ef = __builtin_amdgcn_exp2f(zf);
    float Eg = __builtin_amdgcn_exp2f(zg);   // e^{2 g_raw}
    float eo = __builtin_amdgcn_exp2f(zo);
    float t1  = (1.0f + ei) * (1.0f + Eg);
    float num = c * t1 + (1.0f + ef) * (Eg - 1.0f);
    float D   = t1 * (1.0f + ef);
    c = num * __builtin_amdgcn_rcpf(D);
    float a  = fminf(fmaxf(2.8853900817779268f * c, -24.0f), 24.0f);
    float Ec = __builtin_amdgcn_exp2f(a);    // e^{2c}
    return (Ec - 1.0f) * __builtin_amdgcn_rcpf((1.0f + eo) * (1.0f + Ec));
}

__global__ __launch_bounds__(256, 4) void lstm_fused(
    const float* __restrict__ x,
    const float* __restrict__ W_ih,
    const float* __restrict__ W_hh,
    const float* __restrict__ b_ih,
    const float* __restrict__ b_hh,
    const float* __restrict__ W_lin,
    const float* __restrict__ b_lin,
    float* __restrict__ out)
{
    __shared__ __align__(16) _Float16 hbuf[2][16][HSTR];

    const int tid  = threadIdx.x;
    const int wave = tid >> 6;
    const int lane = tid & 63;
    const int col  = lane & 15;
    const int quad = lane >> 4;
    const int b0   = blockIdx.x * BPB;
    const int j    = wave * 16 + col;

    // ---- init h buffers: zeros; x_0 at even rows col 50; 1.0 at col 51 ----
    for (int i = tid; i < 2 * 16 * HSTR; i += 256)
        (&hbuf[0][0][0])[i] = (_Float16)0.0f;
    __syncthreads();
    if (tid < BPB) {
        hbuf[0][2 * tid][HID]     = (_Float16)x[(size_t)(b0 + tid) * NSTEP];
        hbuf[0][2 * tid][HID + 1] = (_Float16)1.0f;
        hbuf[1][2 * tid][HID + 1] = (_Float16)1.0f;
    }

    // ---- persistent B fragments, prescaled per gate ----
    const float LOG2E = 1.4426950408889634f;
    half8 bfrag[4][2];
    for (int g = 0; g < 4; ++g) {
        const float sc = (g == 2) ? (2.0f * LOG2E) : (-LOG2E);
        for (int kt = 0; kt < 2; ++kt) {
            half8 f;
            #pragma unroll
            for (int jj = 0; jj < 8; ++jj) {
                int k = kt * 32 + quad * 8 + jj;
                float v = 0.0f;
                if (j < HID) {
                    int row = g * HID + j;
                    if (k < HID)           v = W_hh[row * HID + k];
                    else if (k == HID)     v = W_ih[row];
                    else if (k == HID + 1) v = b_ih[row] + b_hh[row];
                }
                f[jj] = (_Float16)(v * sc);
            }
            bfrag[g][kt] = f;
        }
    }

    float c0 = 0.f, c1 = 0.f;   // batch rows 2*quad and 2*quad+1
    const bool xl = (wave == 3) && (quad == 0) && (col < BPB);
    const float* xrow = x + (size_t)(b0 + col) * NSTEP;
    const float4v Z4 = {0.f, 0.f, 0.f, 0.f};

    __syncthreads();

#define MFMA16(A, B, C) __builtin_amdgcn_mfma_f32_16x16x32_f16(A, B, C, 0, 0, 0)
#define STEP(CUR, NXT, T)                                                        \
    {                                                                            \
        float xn = 0.f;                                                          \
        if (xl) {                                                                \
            int tt = ((T) + 1 < NSTEP) ? ((T) + 1) : (NSTEP - 1);                \
            xn = xrow[tt];                                                       \
        }                                                                        \
        const _Float16* arow = &hbuf[CUR][col][0];                               \
        half8 a0 = *(const half8*)(arow + quad * 8);                             \
        half8 a1 = *(const half8*)(arow + 32 + quad * 8);                        \
        float4v d0, d1, d2, d3;                                                  \
        d0 = MFMA16(a0, bfrag[0][0], Z4);                                        \
        d1 = MFMA16(a0, bfrag[1][0], Z4);                                        \
        d2 = MFMA16(a0, bfrag[2][0], Z4);                                        \
        d3 = MFMA16(a0, bfrag[3][0], Z4);                                        \
        d0 = MFMA16(a1, bfrag[0][1], d0);                                        \
        d1 = MFMA16(a1, bfrag[1][1], d1);                                        \
        d2 = MFMA16(a1, bfrag[2][1], d2);                                        \
        d3 = MFMA16(a1, bfrag[3][1], d3);                                        \
        /* valid batch rows live at C-rows quad*4 (r=0) and quad*4+2 (r=2) */    \
        _Float16 h0 = (_Float16)gate_pair(d0[0], d1[0], d2[0], d3[0], c0);       \
        _Float16 h1 = (_Float16)gate_pair(d0[2], d1[2], d2[2], d3[2], c1);       \
        if (j < HID) {                                                           \
            hbuf[NXT][quad * 4][j]     = h0;                                     \
            hbuf[NXT][quad * 4 + 2][j] = h1;                                     \
        }                                                                        \
        if (xl)                                                                  \
            hbuf[NXT][2 * col][HID] = (_Float16)xn;                              \
        __syncthreads();                                                         \
    }

    for (int t = 0; t < NSTEP; t += 2) {
        STEP(0, 1, t)
        STEP(1, 0, t + 1)
    }
#undef STEP
#undef MFMA16

    // ---- epilogue: out[b] = h_last . W_lin + b_lin ; final h is in hbuf[0] ----
    if (tid < BPB) {
        float s = b_lin[0];
        for (int k = 0; k < HID; ++k)
            s += (float)hbuf[0][2 * tid][k] * W_lin[k];
        out[b0 + tid] = s;
    }
}

extern "C" void kernel_launch(void* const* d_in, const int* in_sizes, int n_in,
                              void* d_out, int out_size, void* d_ws, size_t ws_size,
                              hipStream_t stream) {
    const float* x     = (const float*)d_in[0];
    const float* W_ih  = (const float*)d_in[1];
    const float* W_hh  = (const float*)d_in[2];
    const float* b_ih  = (const float*)d_in[3];
    const float* b_hh  = (const float*)d_in[4];
    const float* W_lin = (const float*)d_in[5];
    const float* b_lin = (const float*)d_in[6];
    float* outp = (float*)d_out;
    dim3 grid(8192 / BPB), block(256);
    hipLaunchKernelGGL(lstm_fused, grid, block, 0, stream,
                       x, W_ih, W_hh, b_ih, b_hh, W_lin, b_lin, outp);
}